// Round 1
// baseline (6403.317 us; speedup 1.0000x reference)
//
#include <hip/hip_runtime.h>
#include <hip/hip_bf16.h>

#define BB 4
#define SS 2048
#define DD 1024
#define HH 16
#define HSZ 64
#define DFF 4096

typedef short short8 __attribute__((ext_vector_type(8)));
typedef float f32x4 __attribute__((ext_vector_type(4)));
typedef unsigned short ushort8v __attribute__((ext_vector_type(8)));

__device__ __forceinline__ float bf2f(unsigned short u) {
    return __uint_as_float(((unsigned int)u) << 16);
}

// ---------------- weight repack kernels ----------------
// wq/wk/wv: [H][D][HS] fp32 -> combined W^T [3*D][D] bf16 (row n = output col, contiguous K)
__global__ __launch_bounds__(256) void pack_qkv_kernel(
    const float* __restrict__ wq, const float* __restrict__ wk,
    const float* __restrict__ wv, __hip_bfloat16* __restrict__ out)
{
    int id = blockIdx.x * 256 + threadIdx.x;      // over 3072*1024
    int n = id >> 10;
    int k = id & 1023;
    int sel = n >> 10;
    int hn = n & 1023;
    int h = hn >> 6, e = hn & 63;
    const float* src = (sel == 0) ? wq : (sel == 1) ? wk : wv;
    out[id] = __float2bfloat16(src[(size_t)h * (DD * HSZ) + (size_t)k * HSZ + e]);
}

// in: [K][N] fp32 -> out: [N][K] bf16
__global__ __launch_bounds__(256) void pack_T_kernel(
    const float* __restrict__ in, __hip_bfloat16* __restrict__ out, int K, int N)
{
    int id = blockIdx.x * 256 + threadIdx.x;      // over N*K
    int n = id / K;
    int k = id - n * K;
    out[id] = __float2bfloat16(in[(size_t)k * N + n]);
}

// ---------------- layernorm ----------------
__global__ __launch_bounds__(256) void ln_kernel(
    const float* __restrict__ x, const float* __restrict__ g,
    const float* __restrict__ b, __hip_bfloat16* __restrict__ out)
{
    int row = blockIdx.x;
    int t = threadIdx.x;
    const float4* xr = (const float4*)(x + (size_t)row * DD);
    float4 v = xr[t];
    float s = v.x + v.y + v.z + v.w;
    float ss = v.x * v.x + v.y * v.y + v.z * v.z + v.w * v.w;
    #pragma unroll
    for (int off = 32; off; off >>= 1) {
        s += __shfl_xor(s, off, 64);
        ss += __shfl_xor(ss, off, 64);
    }
    __shared__ float red[8];
    int w = t >> 6, lane = t & 63;
    if (lane == 0) { red[w] = s; red[4 + w] = ss; }
    __syncthreads();
    s = red[0] + red[1] + red[2] + red[3];
    ss = red[4] + red[5] + red[6] + red[7];
    float mu = s * (1.f / DD);
    float var = ss * (1.f / DD) - mu * mu;
    float rs = rsqrtf(var + 1e-5f);
    float4 gv = ((const float4*)g)[t];
    float4 bv = ((const float4*)b)[t];
    unsigned short o0 = __bfloat16_as_ushort(__float2bfloat16((v.x - mu) * rs * gv.x + bv.x));
    unsigned short o1 = __bfloat16_as_ushort(__float2bfloat16((v.y - mu) * rs * gv.y + bv.y));
    unsigned short o2 = __bfloat16_as_ushort(__float2bfloat16((v.z - mu) * rs * gv.z + bv.z));
    unsigned short o3 = __bfloat16_as_ushort(__float2bfloat16((v.w - mu) * rs * gv.w + bv.w));
    ushort4 pk = make_ushort4(o0, o1, o2, o3);
    *(ushort4*)((unsigned short*)out + (size_t)row * DD + t * 4) = pk;
}

// ---------------- bf16 MFMA GEMM: C[M,N] = A[M,K] @ BT[N,K]^T ----------------
// 128x128 tile, BK=32, 4 waves each computing 64x64 (4x4 fragments of 16x16x32)
template<bool BIAS, bool RELU, bool RES, bool OUTF32>
__global__ __launch_bounds__(256) void gemm_kernel(
    const __hip_bfloat16* __restrict__ A, const __hip_bfloat16* __restrict__ BT,
    const float* __restrict__ bias, const float* __restrict__ res,
    void* __restrict__ Cout, int M, int N, int K)
{
    __shared__ uint4 As[512];   // frag (r,kb) at slot r*4 + (kb ^ ((r>>1)&3))
    __shared__ uint4 Bs[512];
    const int t = threadIdx.x;
    const int lane = t & 63, w = t >> 6;
    const int row0 = blockIdx.y * 128, col0 = blockIdx.x * 128;
    const int wr = (w >> 1) * 64, wc = (w & 1) * 64;
    const int lr = lane & 15, kb = lane >> 4;
    f32x4 acc[4][4] = {};

    for (int k0 = 0; k0 < K; k0 += 32) {
        __syncthreads();
        #pragma unroll
        for (int j = 0; j < 2; ++j) {
            int f = t + j * 256;
            int r = f >> 2, fkb = f & 3;
            int slot = r * 4 + (fkb ^ ((r >> 1) & 3));
            As[slot] = *(const uint4*)(A + (size_t)(row0 + r) * K + k0 + fkb * 8);
            Bs[slot] = *(const uint4*)(BT + (size_t)(col0 + r) * K + k0 + fkb * 8);
        }
        __syncthreads();
        short8 af[4], bfr[4];
        #pragma unroll
        for (int m = 0; m < 4; ++m) {
            int r = wr + m * 16 + lr;
            af[m] = *(const short8*)&As[r * 4 + (kb ^ ((r >> 1) & 3))];
        }
        #pragma unroll
        for (int n = 0; n < 4; ++n) {
            int c = wc + n * 16 + lr;
            bfr[n] = *(const short8*)&Bs[c * 4 + (kb ^ ((c >> 1) & 3))];
        }
        #pragma unroll
        for (int m = 0; m < 4; ++m)
            #pragma unroll
            for (int n = 0; n < 4; ++n)
                acc[m][n] = __builtin_amdgcn_mfma_f32_16x16x32_bf16(af[m], bfr[n], acc[m][n], 0, 0, 0);
    }

    #pragma unroll
    for (int m = 0; m < 4; ++m) {
        #pragma unroll
        for (int j = 0; j < 4; ++j) {
            int rr = row0 + wr + m * 16 + (lane >> 4) * 4 + j;
            #pragma unroll
            for (int n = 0; n < 4; ++n) {
                int cc = col0 + wc + n * 16 + lr;
                float vv = acc[m][n][j];
                if (BIAS) vv += bias[cc];
                if (RELU) vv = fmaxf(vv, 0.f);
                if (RES) vv += res[(size_t)rr * N + cc];
                if (OUTF32) ((float*)Cout)[(size_t)rr * N + cc] = vv;
                else ((__hip_bfloat16*)Cout)[(size_t)rr * N + cc] = __float2bfloat16(vv);
            }
        }
    }
}

// ---------------- causal attention, 1 wave per (b,h,s) query row ----------------
// qkv: [B*S][3072] bf16 (cols 0..1023=q, 1024..2047=k, 2048..3071=v, each [H][HS])
// o:   [B*S][1024] bf16
__global__ __launch_bounds__(256) void attn_kernel(
    const __hip_bfloat16* __restrict__ qkv, __hip_bfloat16* __restrict__ o)
{
    const int wid = threadIdx.x >> 6, lane = threadIdx.x & 63;
    const int row = blockIdx.x * 4 + wid;           // [0, B*H*S)
    const int s = row & (SS - 1);
    const int bh = row >> 11;
    const int b = bh >> 4, h = bh & 15;
    const unsigned short* base = (const unsigned short*)qkv + (size_t)(b * SS) * 3072 + h * HSZ;

    float qv = bf2f(base[(size_t)s * 3072 + lane]);   // lane owns q[lane]
    float m_run = -INFINITY, l_run = 0.f, oacc = 0.f;
    const int nch = (s >> 6) + 1;

    for (int c = 0; c < nch; ++c) {
        int tk = c * 64 + lane;
        // ---- scores: lane owns key-row tk ----
        const unsigned short* krow = base + (size_t)tk * 3072 + DD;
        float sc = 0.f;
        #pragma unroll
        for (int e8 = 0; e8 < 8; ++e8) {
            ushort8v kv = *(const ushort8v*)(krow + e8 * 8);
            #pragma unroll
            for (int i = 0; i < 8; ++i)
                sc += __shfl(qv, e8 * 8 + i, 64) * bf2f(kv[i]);
        }
        sc *= 0.125f;
        bool valid = (tk <= s);
        if (!valid) sc = -INFINITY;
        float cm = sc;
        #pragma unroll
        for (int off = 32; off; off >>= 1) cm = fmaxf(cm, __shfl_xor(cm, off, 64));
        float mn = fmaxf(m_run, cm);
        float p = valid ? __expf(sc - mn) : 0.f;
        float corr = __expf(m_run - mn);              // first chunk: exp(-inf)=0
        float csum = p;
        #pragma unroll
        for (int off = 32; off; off >>= 1) csum += __shfl_xor(csum, off, 64);
        l_run = l_run * corr + csum;
        m_run = mn;
        oacc *= corr;
        // ---- PV: lane owns output dim e=lane ----
        const unsigned short* vbase = base + 2 * DD + (size_t)(c * 64) * 3072;
        int tmax = min(64, s - c * 64 + 1);
        for (int tt = 0; tt < tmax; ++tt) {
            float pt = __shfl(p, tt, 64);
            oacc += pt * bf2f(vbase[(size_t)tt * 3072 + lane]);
        }
    }
    float outv = oacc / l_run;
    o[(size_t)(b * SS + s) * DD + h * HSZ + lane] = __float2bfloat16(outv);
}

// ---------------- launch ----------------
extern "C" void kernel_launch(void* const* d_in, const int* in_sizes, int n_in,
                              void* d_out, int out_size, void* d_ws, size_t ws_size,
                              hipStream_t stream)
{
    const float* x      = (const float*)d_in[0];
    const float* wq     = (const float*)d_in[1];
    const float* wk     = (const float*)d_in[2];
    const float* wv     = (const float*)d_in[3];
    const float* proj_w = (const float*)d_in[4];
    const float* proj_b = (const float*)d_in[5];
    const float* ff1_w  = (const float*)d_in[6];
    const float* ff1_b  = (const float*)d_in[7];
    const float* ff2_w  = (const float*)d_in[8];
    const float* ff2_b  = (const float*)d_in[9];
    const float* ln1_g  = (const float*)d_in[10];
    const float* ln1_b  = (const float*)d_in[11];
    const float* ln2_g  = (const float*)d_in[12];
    const float* ln2_b  = (const float*)d_in[13];
    float* out = (float*)d_out;

    char* ws = (char*)d_ws;
    const size_t MB = 1ull << 20;
    __hip_bfloat16* h     = (__hip_bfloat16*)(ws);              // 16MB (h / h2)
    __hip_bfloat16* qkv   = (__hip_bfloat16*)(ws + 16 * MB);    // 48MB
    __hip_bfloat16* obuf  = (__hip_bfloat16*)(ws + 64 * MB);    // 16MB
    float*          x1    = (float*)(ws + 80 * MB);             // 32MB
    __hip_bfloat16* wqkvT = (__hip_bfloat16*)(ws + 112 * MB);   // 6MB
    __hip_bfloat16* projT = (__hip_bfloat16*)(ws + 118 * MB);   // 2MB
    __hip_bfloat16* ff1T  = (__hip_bfloat16*)(ws + 120 * MB);   // 8MB
    __hip_bfloat16* ff2T  = (__hip_bfloat16*)(ws + 128 * MB);   // 8MB
    __hip_bfloat16* f1    = (__hip_bfloat16*)(ws + 16 * MB);    // 64MB, aliases qkv+obuf (dead by then)

    const int ROWS = BB * SS;   // 8192

    // weight repack (bf16, transposed to [N][K])
    pack_qkv_kernel<<<(3 * DD * DD) / 256, 256, 0, stream>>>(wq, wk, wv, wqkvT);
    pack_T_kernel<<<(DD * DD) / 256, 256, 0, stream>>>(proj_w, projT, DD, DD);
    pack_T_kernel<<<(DD * DFF) / 256, 256, 0, stream>>>(ff1_w, ff1T, DD, DFF);
    pack_T_kernel<<<(DFF * DD) / 256, 256, 0, stream>>>(ff2_w, ff2T, DFF, DD);

    // ln1(x) -> h
    ln_kernel<<<ROWS, 256, 0, stream>>>(x, ln1_g, ln1_b, h);
    // qkv = h @ Wqkv   [8192 x 3072]
    gemm_kernel<false, false, false, false><<<dim3(3 * DD / 128, ROWS / 128), 256, 0, stream>>>(
        h, wqkvT, nullptr, nullptr, qkv, ROWS, 3 * DD, DD);
    // attention -> obuf
    attn_kernel<<<(BB * HH * SS) / 4, 256, 0, stream>>>(qkv, obuf);
    // x1 = x + obuf @ proj_w + proj_b
    gemm_kernel<true, false, true, true><<<dim3(DD / 128, ROWS / 128), 256, 0, stream>>>(
        obuf, projT, proj_b, x, x1, ROWS, DD, DD);
    // ln2(x1) -> h
    ln_kernel<<<ROWS, 256, 0, stream>>>(x1, ln2_g, ln2_b, h);
    // f1 = relu(h @ ff1_w + ff1_b)   [8192 x 4096]
    gemm_kernel<true, true, false, false><<<dim3(DFF / 128, ROWS / 128), 256, 0, stream>>>(
        h, ff1T, ff1_b, nullptr, f1, ROWS, DFF, DD);
    // out = x1 + f1 @ ff2_w + ff2_b
    gemm_kernel<true, false, true, true><<<dim3(DD / 128, ROWS / 128), 256, 0, stream>>>(
        f1, ff2T, ff2_b, x1, out, ROWS, DD, DFF);
}

// Round 2
// 573.392 us; speedup vs baseline: 11.1674x; 11.1674x over previous
//
#include <hip/hip_runtime.h>
#include <hip/hip_bf16.h>

#define BB 4
#define SS 2048
#define DD 1024
#define HH 16
#define HSZ 64
#define DFF 4096

typedef short short8 __attribute__((ext_vector_type(8)));
typedef float f32x4 __attribute__((ext_vector_type(4)));
typedef unsigned short us4 __attribute__((ext_vector_type(4)));

#define AS1 __attribute__((address_space(1)))
#define AS3 __attribute__((address_space(3)))

__device__ __forceinline__ unsigned short f2bf(float f) {
    return __bfloat16_as_ushort(__float2bfloat16(f));
}

// ---------------- weight repack kernels ----------------
__global__ __launch_bounds__(256) void pack_qkv_kernel(
    const float* __restrict__ wq, const float* __restrict__ wk,
    const float* __restrict__ wv, __hip_bfloat16* __restrict__ out)
{
    int id = blockIdx.x * 256 + threadIdx.x;      // over 3072*1024
    int n = id >> 10;
    int k = id & 1023;
    int sel = n >> 10;
    int hn = n & 1023;
    int h = hn >> 6, e = hn & 63;
    const float* src = (sel == 0) ? wq : (sel == 1) ? wk : wv;
    out[id] = __float2bfloat16(src[(size_t)h * (DD * HSZ) + (size_t)k * HSZ + e]);
}

__global__ __launch_bounds__(256) void pack_T_kernel(
    const float* __restrict__ in, __hip_bfloat16* __restrict__ out, int K, int N)
{
    int id = blockIdx.x * 256 + threadIdx.x;      // over N*K
    int n = id / K;
    int k = id - n * K;
    out[id] = __float2bfloat16(in[(size_t)k * N + n]);
}

// ---------------- layernorm ----------------
__global__ __launch_bounds__(256) void ln_kernel(
    const float* __restrict__ x, const float* __restrict__ g,
    const float* __restrict__ b, __hip_bfloat16* __restrict__ out)
{
    int row = blockIdx.x;
    int t = threadIdx.x;
    const float4* xr = (const float4*)(x + (size_t)row * DD);
    float4 v = xr[t];
    float s = v.x + v.y + v.z + v.w;
    float ss = v.x * v.x + v.y * v.y + v.z * v.z + v.w * v.w;
    #pragma unroll
    for (int off = 32; off; off >>= 1) {
        s += __shfl_xor(s, off, 64);
        ss += __shfl_xor(ss, off, 64);
    }
    __shared__ float red[8];
    int w = t >> 6, lane = t & 63;
    if (lane == 0) { red[w] = s; red[4 + w] = ss; }
    __syncthreads();
    s = red[0] + red[1] + red[2] + red[3];
    ss = red[4] + red[5] + red[6] + red[7];
    float mu = s * (1.f / DD);
    float var = ss * (1.f / DD) - mu * mu;
    float rs = rsqrtf(var + 1e-5f);
    float4 gv = ((const float4*)g)[t];
    float4 bv = ((const float4*)b)[t];
    ushort4 pk = make_ushort4(
        f2bf((v.x - mu) * rs * gv.x + bv.x),
        f2bf((v.y - mu) * rs * gv.y + bv.y),
        f2bf((v.z - mu) * rs * gv.z + bv.z),
        f2bf((v.w - mu) * rs * gv.w + bv.w));
    *(ushort4*)((unsigned short*)out + (size_t)row * DD + t * 4) = pk;
}

// ---------------- bf16 MFMA GEMM: C[M,N] = A[M,K] @ BT[N,K]^T ----------------
// 128x128 tile, BK=32, 4 waves each computing 64x64 (4x4 fragments of 16x16x32)
// Staging via global_load_lds width=16: linear LDS dest, inverse-swizzled global src.
template<bool BIAS, bool RELU, bool RES, bool OUTF32>
__global__ __launch_bounds__(256) void gemm_kernel(
    const __hip_bfloat16* __restrict__ A, const __hip_bfloat16* __restrict__ BT,
    const float* __restrict__ bias, const float* __restrict__ res,
    void* __restrict__ Cout, int M, int N, int K)
{
    __shared__ uint4 As[512];   // frag (r,kb) at slot r*4 + (kb ^ ((r>>1)&3))
    __shared__ uint4 Bs[512];
    const int t = threadIdx.x;
    const int lane = t & 63, w = t >> 6;
    const int row0 = blockIdx.y * 128, col0 = blockIdx.x * 128;
    const int wr = (w >> 1) * 64, wc = (w & 1) * 64;
    const int lr = lane & 15, kb = lane >> 4;
    f32x4 acc[4][4] = {};

    for (int k0 = 0; k0 < K; k0 += 32) {
        __syncthreads();
        #pragma unroll
        for (int j = 0; j < 2; ++j) {
            int s = w * 128 + j * 64 + lane;
            int r = s >> 2;
            int fkb = (s & 3) ^ ((r >> 1) & 3);
            const __hip_bfloat16* asrc = A + (size_t)(row0 + r) * K + k0 + fkb * 8;
            const __hip_bfloat16* bsrc = BT + (size_t)(col0 + r) * K + k0 + fkb * 8;
            __builtin_amdgcn_global_load_lds((const AS1 void*)asrc, (AS3 void*)&As[w * 128 + j * 64], 16, 0, 0);
            __builtin_amdgcn_global_load_lds((const AS1 void*)bsrc, (AS3 void*)&Bs[w * 128 + j * 64], 16, 0, 0);
        }
        __syncthreads();
        short8 af[4], bfr[4];
        #pragma unroll
        for (int m = 0; m < 4; ++m) {
            int r = wr + m * 16 + lr;
            af[m] = *(const short8*)&As[r * 4 + (kb ^ ((r >> 1) & 3))];
        }
        #pragma unroll
        for (int n = 0; n < 4; ++n) {
            int c = wc + n * 16 + lr;
            bfr[n] = *(const short8*)&Bs[c * 4 + (kb ^ ((c >> 1) & 3))];
        }
        #pragma unroll
        for (int m = 0; m < 4; ++m)
            #pragma unroll
            for (int n = 0; n < 4; ++n)
                acc[m][n] = __builtin_amdgcn_mfma_f32_16x16x32_bf16(af[m], bfr[n], acc[m][n], 0, 0, 0);
    }

    #pragma unroll
    for (int m = 0; m < 4; ++m) {
        #pragma unroll
        for (int j = 0; j < 4; ++j) {
            int rr = row0 + wr + m * 16 + (lane >> 4) * 4 + j;
            #pragma unroll
            for (int n = 0; n < 4; ++n) {
                int cc = col0 + wc + n * 16 + lr;
                float vv = acc[m][n][j];
                if (BIAS) vv += bias[cc];
                if (RELU) vv = fmaxf(vv, 0.f);
                if (RES) vv += res[(size_t)rr * N + cc];
                if (OUTF32) ((float*)Cout)[(size_t)rr * N + cc] = vv;
                else ((__hip_bfloat16*)Cout)[(size_t)rr * N + cc] = __float2bfloat16(vv);
            }
        }
    }
}

// ---------------- MFMA flash attention ----------------
// Block = (b, h, 64 q-rows); 4 waves x 16 q-rows. KV tiles of 64.
// Swapped QK^T: S^T = mfma(K, Q) so lane owns 16 kv for one q column.
// LDS XOR swizzle: element addr = row*64 + ((chunk16) ^ (row&7))*8 + within.
__global__ __launch_bounds__(256) void attn_kernel(
    const __hip_bfloat16* __restrict__ qkv, __hip_bfloat16* __restrict__ o)
{
    __shared__ unsigned short K_lds[64 * 64];
    __shared__ unsigned short Vt_lds[64 * 64];
    __shared__ unsigned short P_lds[4 * 16 * 64];

    const int t = threadIdx.x;
    const int lane = t & 63, w = t >> 6;
    const int q = lane & 15, g = lane >> 4;
    const int bid = blockIdx.x;
    const int qt = bid & 31;
    const int h = (bid >> 5) & 15;
    const int b = bid >> 9;
    const int q0 = qt * 64;
    const unsigned short* qkvu = (const unsigned short*)qkv;
    const size_t rowbase = (size_t)(b * SS) * 3072;

    // Q fragments (B-operand: col=q=lane&15, k=(lane>>4)*8+i, +32 per kk)
    const int qg = q0 + w * 16 + q;
    short8 qf[2];
    #pragma unroll
    for (int kk = 0; kk < 2; ++kk)
        qf[kk] = *(const short8*)(qkvu + rowbase + (size_t)qg * 3072 + h * HSZ + kk * 32 + g * 8);

    f32x4 oacc[4] = {};
    float m_run = -1e30f, l_run = 0.f;
    const int nt = qt + 1;

    for (int it = 0; it < nt; ++it) {
        const int kv0 = it * 64;
        __syncthreads();
        // ---- stage K [64 kv][64 d], swizzled ----
        {
            int kv = t >> 2, c = t & 3;
            const unsigned short* src = qkvu + rowbase + (size_t)(kv0 + kv) * 3072 + DD + h * HSZ + c * 16;
            uint4 v0 = *(const uint4*)src;
            uint4 v1 = *(const uint4*)(src + 8);
            int sw = kv & 7;
            *(uint4*)&K_lds[kv * 64 + ((2 * c) ^ sw) * 8] = v0;
            *(uint4*)&K_lds[kv * 64 + ((2 * c + 1) ^ sw) * 8] = v1;
        }
        // ---- stage V transposed [64 d][64 kv], swizzled ----
        {
            int bkv = t >> 4, bd = t & 15;
            const unsigned short* src = qkvu + rowbase + (size_t)(kv0 + bkv * 4) * 3072 + 2 * DD + h * HSZ + bd * 4;
            us4 r0 = *(const us4*)src;
            us4 r1 = *(const us4*)(src + 3072);
            us4 r2 = *(const us4*)(src + 2 * 3072);
            us4 r3 = *(const us4*)(src + 3 * 3072);
            #pragma unroll
            for (int cc = 0; cc < 4; ++cc) {
                int d = bd * 4 + cc;
                us4 wv = { r0[cc], r1[cc], r2[cc], r3[cc] };
                *(us4*)&Vt_lds[d * 64 + (((bkv >> 1) ^ (d & 7)) * 8) + (bkv & 1) * 4] = wv;
            }
        }
        __syncthreads();

        // ---- S^T = K @ Q^T : st[tt][j] has kv = kv0+tt*16+g*4+j, for q-col qg ----
        f32x4 st[4] = {};
        #pragma unroll
        for (int tt = 0; tt < 4; ++tt) {
            #pragma unroll
            for (int kk = 0; kk < 2; ++kk) {
                short8 kf = *(const short8*)&K_lds[(tt * 16 + q) * 64 + ((4 * kk + g) ^ (q & 7)) * 8];
                st[tt] = __builtin_amdgcn_mfma_f32_16x16x32_bf16(kf, qf[kk], st[tt], 0, 0, 0);
            }
        }

        // ---- online softmax (16 lane-local + 2 shuffles) ----
        float mt = -1e30f;
        #pragma unroll
        for (int tt = 0; tt < 4; ++tt)
            #pragma unroll
            for (int j = 0; j < 4; ++j) {
                float s = st[tt][j] * 0.125f;
                int kvg = kv0 + tt * 16 + g * 4 + j;
                s = (kvg <= qg) ? s : -1e30f;
                st[tt][j] = s;
                mt = fmaxf(mt, s);
            }
        mt = fmaxf(mt, __shfl_xor(mt, 16, 64));
        mt = fmaxf(mt, __shfl_xor(mt, 32, 64));
        float m_new = fmaxf(m_run, mt);
        float corr = __expf(m_run - m_new);
        float lsum = 0.f;
        #pragma unroll
        for (int tt = 0; tt < 4; ++tt)
            #pragma unroll
            for (int j = 0; j < 4; ++j) {
                float p = __expf(st[tt][j] - m_new);
                st[tt][j] = p;
                lsum += p;
            }
        lsum += __shfl_xor(lsum, 16, 64);
        lsum += __shfl_xor(lsum, 32, 64);
        l_run = l_run * corr + lsum;
        m_run = m_new;

        // ---- P -> wave-private LDS (bf16), layout [q][kv] swizzled ----
        #pragma unroll
        for (int tt = 0; tt < 4; ++tt) {
            unsigned int lo = ((unsigned int)f2bf(st[tt][1]) << 16) | (unsigned int)f2bf(st[tt][0]);
            unsigned int hi = ((unsigned int)f2bf(st[tt][3]) << 16) | (unsigned int)f2bf(st[tt][2]);
            uint2 pk = make_uint2(lo, hi);
            *(uint2*)&P_lds[w * 1024 + q * 64 + ((2 * tt + (g >> 1)) ^ (q & 7)) * 8 + (g & 1) * 4] = pk;
        }

        // ---- rescale O (row j of C-layout = q_local g*4+j) ----
        #pragma unroll
        for (int j = 0; j < 4; ++j) {
            float cj = __shfl(corr, g * 4 + j, 64);
            #pragma unroll
            for (int dn = 0; dn < 4; ++dn)
                oacc[dn][j] *= cj;
        }

        // ---- PV: O[16q][64d] += P @ V ----
        #pragma unroll
        for (int kk = 0; kk < 2; ++kk) {
            short8 pf = *(const short8*)&P_lds[w * 1024 + q * 64 + ((4 * kk + g) ^ (q & 7)) * 8];
            #pragma unroll
            for (int dn = 0; dn < 4; ++dn) {
                short8 vf = *(const short8*)&Vt_lds[(dn * 16 + q) * 64 + ((4 * kk + g) ^ (q & 7)) * 8];
                oacc[dn] = __builtin_amdgcn_mfma_f32_16x16x32_bf16(pf, vf, oacc[dn], 0, 0, 0);
            }
        }
    }

    // ---- epilogue: normalize and store ----
    #pragma unroll
    for (int j = 0; j < 4; ++j) {
        float lj = __shfl(l_run, g * 4 + j, 64);
        float inv = 1.f / lj;
        int orow = q0 + w * 16 + g * 4 + j;
        #pragma unroll
        for (int dn = 0; dn < 4; ++dn) {
            unsigned short* op = (unsigned short*)o;
            op[(size_t)(b * SS + orow) * DD + h * HSZ + dn * 16 + q] = f2bf(oacc[dn][j] * inv);
        }
    }
}

// ---------------- launch ----------------
extern "C" void kernel_launch(void* const* d_in, const int* in_sizes, int n_in,
                              void* d_out, int out_size, void* d_ws, size_t ws_size,
                              hipStream_t stream)
{
    const float* x      = (const float*)d_in[0];
    const float* wq     = (const float*)d_in[1];
    const float* wk     = (const float*)d_in[2];
    const float* wv     = (const float*)d_in[3];
    const float* proj_w = (const float*)d_in[4];
    const float* proj_b = (const float*)d_in[5];
    const float* ff1_w  = (const float*)d_in[6];
    const float* ff1_b  = (const float*)d_in[7];
    const float* ff2_w  = (const float*)d_in[8];
    const float* ff2_b  = (const float*)d_in[9];
    const float* ln1_g  = (const float*)d_in[10];
    const float* ln1_b  = (const float*)d_in[11];
    const float* ln2_g  = (const float*)d_in[12];
    const float* ln2_b  = (const float*)d_in[13];
    float* out = (float*)d_out;

    char* ws = (char*)d_ws;
    const size_t MB = 1ull << 20;
    __hip_bfloat16* h     = (__hip_bfloat16*)(ws);              // 16MB (h / h2)
    __hip_bfloat16* qkv   = (__hip_bfloat16*)(ws + 16 * MB);    // 48MB
    __hip_bfloat16* obuf  = (__hip_bfloat16*)(ws + 64 * MB);    // 16MB
    float*          x1    = (float*)(ws + 80 * MB);             // 32MB
    __hip_bfloat16* wqkvT = (__hip_bfloat16*)(ws + 112 * MB);   // 6MB
    __hip_bfloat16* projT = (__hip_bfloat16*)(ws + 118 * MB);   // 2MB
    __hip_bfloat16* ff1T  = (__hip_bfloat16*)(ws + 120 * MB);   // 8MB
    __hip_bfloat16* ff2T  = (__hip_bfloat16*)(ws + 128 * MB);   // 8MB
    __hip_bfloat16* f1    = (__hip_bfloat16*)(ws + 16 * MB);    // 64MB, aliases qkv+obuf (dead by then)

    const int ROWS = BB * SS;   // 8192

    pack_qkv_kernel<<<(3 * DD * DD) / 256, 256, 0, stream>>>(wq, wk, wv, wqkvT);
    pack_T_kernel<<<(DD * DD) / 256, 256, 0, stream>>>(proj_w, projT, DD, DD);
    pack_T_kernel<<<(DD * DFF) / 256, 256, 0, stream>>>(ff1_w, ff1T, DD, DFF);
    pack_T_kernel<<<(DFF * DD) / 256, 256, 0, stream>>>(ff2_w, ff2T, DFF, DD);

    ln_kernel<<<ROWS, 256, 0, stream>>>(x, ln1_g, ln1_b, h);
    gemm_kernel<false, false, false, false><<<dim3(3 * DD / 128, ROWS / 128), 256, 0, stream>>>(
        h, wqkvT, nullptr, nullptr, qkv, ROWS, 3 * DD, DD);
    attn_kernel<<<BB * HH * (SS / 64), 256, 0, stream>>>(qkv, obuf);
    gemm_kernel<true, false, true, true><<<dim3(DD / 128, ROWS / 128), 256, 0, stream>>>(
        obuf, projT, proj_b, x, x1, ROWS, DD, DD);
    ln_kernel<<<ROWS, 256, 0, stream>>>(x1, ln2_g, ln2_b, h);
    gemm_kernel<true, true, false, false><<<dim3(DFF / 128, ROWS / 128), 256, 0, stream>>>(
        h, ff1T, ff1_b, nullptr, f1, ROWS, DFF, DD);
    gemm_kernel<true, false, true, true><<<dim3(DD / 128, ROWS / 128), 256, 0, stream>>>(
        f1, ff2T, ff2_b, x1, out, ROWS, DD, DFF);
}

// Round 3
// 513.854 us; speedup vs baseline: 12.4614x; 1.1159x over previous
//
#include <hip/hip_runtime.h>
#include <hip/hip_bf16.h>

#define BB 4
#define SS 2048
#define DD 1024
#define HH 16
#define HSZ 64
#define DFF 4096

typedef short short8 __attribute__((ext_vector_type(8)));
typedef float f32x4 __attribute__((ext_vector_type(4)));
typedef unsigned short us4 __attribute__((ext_vector_type(4)));

#define AS1 __attribute__((address_space(1)))
#define AS3 __attribute__((address_space(3)))

__device__ __forceinline__ unsigned short f2bf(float f) {
    return __bfloat16_as_ushort(__float2bfloat16(f));
}

// ---------------- weight repack kernels ----------------
__global__ __launch_bounds__(256) void pack_qkv_kernel(
    const float* __restrict__ wq, const float* __restrict__ wk,
    const float* __restrict__ wv, __hip_bfloat16* __restrict__ out)
{
    int id = blockIdx.x * 256 + threadIdx.x;      // over 3072*1024
    int n = id >> 10;
    int k = id & 1023;
    int sel = n >> 10;
    int hn = n & 1023;
    int h = hn >> 6, e = hn & 63;
    const float* src = (sel == 0) ? wq : (sel == 1) ? wk : wv;
    out[id] = __float2bfloat16(src[(size_t)h * (DD * HSZ) + (size_t)k * HSZ + e]);
}

__global__ __launch_bounds__(256) void pack_T_kernel(
    const float* __restrict__ in, __hip_bfloat16* __restrict__ out, int K, int N)
{
    int id = blockIdx.x * 256 + threadIdx.x;      // over N*K
    int n = id / K;
    int k = id - n * K;
    out[id] = __float2bfloat16(in[(size_t)k * N + n]);
}

// ---------------- layernorm ----------------
__global__ __launch_bounds__(256) void ln_kernel(
    const float* __restrict__ x, const float* __restrict__ g,
    const float* __restrict__ b, __hip_bfloat16* __restrict__ out)
{
    int row = blockIdx.x;
    int t = threadIdx.x;
    const float4* xr = (const float4*)(x + (size_t)row * DD);
    float4 v = xr[t];
    float s = v.x + v.y + v.z + v.w;
    float ss = v.x * v.x + v.y * v.y + v.z * v.z + v.w * v.w;
    #pragma unroll
    for (int off = 32; off; off >>= 1) {
        s += __shfl_xor(s, off, 64);
        ss += __shfl_xor(ss, off, 64);
    }
    __shared__ float red[8];
    int w = t >> 6, lane = t & 63;
    if (lane == 0) { red[w] = s; red[4 + w] = ss; }
    __syncthreads();
    s = red[0] + red[1] + red[2] + red[3];
    ss = red[4] + red[5] + red[6] + red[7];
    float mu = s * (1.f / DD);
    float var = ss * (1.f / DD) - mu * mu;
    float rs = rsqrtf(var + 1e-5f);
    float4 gv = ((const float4*)g)[t];
    float4 bv = ((const float4*)b)[t];
    ushort4 pk = make_ushort4(
        f2bf((v.x - mu) * rs * gv.x + bv.x),
        f2bf((v.y - mu) * rs * gv.y + bv.y),
        f2bf((v.z - mu) * rs * gv.z + bv.z),
        f2bf((v.w - mu) * rs * gv.w + bv.w));
    *(ushort4*)((unsigned short*)out + (size_t)row * DD + t * 4) = pk;
}

// ---------------- bf16 MFMA GEMM: C[M,N] = A[M,K] @ BT[N,K]^T ----------------
template<bool BIAS, bool RELU, bool RES, bool OUTF32>
__global__ __launch_bounds__(256) void gemm_kernel(
    const __hip_bfloat16* __restrict__ A, const __hip_bfloat16* __restrict__ BT,
    const float* __restrict__ bias, const float* __restrict__ res,
    void* __restrict__ Cout, int M, int N, int K)
{
    __shared__ uint4 As[512];   // frag (r,kb) at slot r*4 + (kb ^ ((r>>1)&3))
    __shared__ uint4 Bs[512];
    const int t = threadIdx.x;
    const int lane = t & 63, w = t >> 6;
    const int row0 = blockIdx.y * 128, col0 = blockIdx.x * 128;
    const int wr = (w >> 1) * 64, wc = (w & 1) * 64;
    const int lr = lane & 15, kb = lane >> 4;
    f32x4 acc[4][4] = {};

    for (int k0 = 0; k0 < K; k0 += 32) {
        __syncthreads();
        #pragma unroll
        for (int j = 0; j < 2; ++j) {
            int s = w * 128 + j * 64 + lane;
            int r = s >> 2;
            int fkb = (s & 3) ^ ((r >> 1) & 3);
            const __hip_bfloat16* asrc = A + (size_t)(row0 + r) * K + k0 + fkb * 8;
            const __hip_bfloat16* bsrc = BT + (size_t)(col0 + r) * K + k0 + fkb * 8;
            __builtin_amdgcn_global_load_lds((const AS1 void*)asrc, (AS3 void*)&As[w * 128 + j * 64], 16, 0, 0);
            __builtin_amdgcn_global_load_lds((const AS1 void*)bsrc, (AS3 void*)&Bs[w * 128 + j * 64], 16, 0, 0);
        }
        __syncthreads();
        short8 af[4], bfr[4];
        #pragma unroll
        for (int m = 0; m < 4; ++m) {
            int r = wr + m * 16 + lr;
            af[m] = *(const short8*)&As[r * 4 + (kb ^ ((r >> 1) & 3))];
        }
        #pragma unroll
        for (int n = 0; n < 4; ++n) {
            int c = wc + n * 16 + lr;
            bfr[n] = *(const short8*)&Bs[c * 4 + (kb ^ ((c >> 1) & 3))];
        }
        #pragma unroll
        for (int m = 0; m < 4; ++m)
            #pragma unroll
            for (int n = 0; n < 4; ++n)
                acc[m][n] = __builtin_amdgcn_mfma_f32_16x16x32_bf16(af[m], bfr[n], acc[m][n], 0, 0, 0);
    }

    #pragma unroll
    for (int m = 0; m < 4; ++m) {
        #pragma unroll
        for (int j = 0; j < 4; ++j) {
            int rr = row0 + wr + m * 16 + (lane >> 4) * 4 + j;
            #pragma unroll
            for (int n = 0; n < 4; ++n) {
                int cc = col0 + wc + n * 16 + lr;
                float vv = acc[m][n][j];
                if (BIAS) vv += bias[cc];
                if (RELU) vv = fmaxf(vv, 0.f);
                if (RES) vv += res[(size_t)rr * N + cc];
                if (OUTF32) ((float*)Cout)[(size_t)rr * N + cc] = vv;
                else ((__hip_bfloat16*)Cout)[(size_t)rr * N + cc] = __float2bfloat16(vv);
            }
        }
    }
}

// ---------------- MFMA flash attention, causally balanced ----------------
// Block = (b, h, q-tile pair {pq, 31-pq}); 8 waves (512 thr).
// Waves 0-3: q-tile pq (16 q-rows each). Waves 4-7: q-tile 31-pq.
// Shared K/V staging per 64-kv tile: K by waves 0-3, V-transpose by waves 4-7.
// Every block runs nt = 32-pq tiles -> uniform work, no causal tail.
__global__ __launch_bounds__(512) void attn_kernel(
    const __hip_bfloat16* __restrict__ qkv, __hip_bfloat16* __restrict__ o)
{
    __shared__ unsigned short K_lds[64 * 64];
    __shared__ unsigned short Vt_lds[64 * 64];
    __shared__ unsigned short P_lds[8 * 16 * 64];

    const int t = threadIdx.x;
    const int lane = t & 63, w = t >> 6;
    const int grp = w >> 2, wq4 = w & 3;
    const int q = lane & 15, g = lane >> 4;
    const int pq = blockIdx.x & 15;
    const int h = (blockIdx.x >> 4) & 15;
    const int b = blockIdx.x >> 8;
    const int qt = grp ? (31 - pq) : pq;
    const int q0 = qt * 64;
    const unsigned short* qkvu = (const unsigned short*)qkv;
    const size_t rowbase = (size_t)(b * SS) * 3072;

    // Q fragments (B-operand: col=q=lane&15, k=(lane>>4)*8+i, +32 per kk)
    const int qg = q0 + wq4 * 16 + q;
    short8 qf[2];
    #pragma unroll
    for (int kk = 0; kk < 2; ++kk)
        qf[kk] = *(const short8*)(qkvu + rowbase + (size_t)qg * 3072 + h * HSZ + kk * 32 + g * 8);

    f32x4 oacc[4] = {};
    float m_run = -1e30f, l_run = 0.f;
    const int nt = 32 - pq;        // tiles the block iterates (group 1's need)
    const int myNt = qt + 1;       // tiles this wave computes

    for (int it = 0; it < nt; ++it) {
        const int kv0 = it * 64;
        __syncthreads();
        if (t < 256) {
            // ---- stage K [64 kv][64 d], swizzled (waves 0-3) ----
            int kv = t >> 2, c = t & 3;
            const unsigned short* src = qkvu + rowbase + (size_t)(kv0 + kv) * 3072 + DD + h * HSZ + c * 16;
            uint4 v0 = *(const uint4*)src;
            uint4 v1 = *(const uint4*)(src + 8);
            int sw = kv & 7;
            *(uint4*)&K_lds[kv * 64 + ((2 * c) ^ sw) * 8] = v0;
            *(uint4*)&K_lds[kv * 64 + ((2 * c + 1) ^ sw) * 8] = v1;
        } else {
            // ---- stage V transposed [64 d][64 kv], swizzled (waves 4-7) ----
            int t2 = t - 256;
            int bkv = t2 >> 4, bd = t2 & 15;
            const unsigned short* src = qkvu + rowbase + (size_t)(kv0 + bkv * 4) * 3072 + 2 * DD + h * HSZ + bd * 4;
            us4 r0 = *(const us4*)src;
            us4 r1 = *(const us4*)(src + 3072);
            us4 r2 = *(const us4*)(src + 2 * 3072);
            us4 r3 = *(const us4*)(src + 3 * 3072);
            #pragma unroll
            for (int cc = 0; cc < 4; ++cc) {
                int d = bd * 4 + cc;
                us4 wv = { r0[cc], r1[cc], r2[cc], r3[cc] };
                *(us4*)&Vt_lds[d * 64 + (((bkv >> 1) ^ (d & 7)) * 8) + (bkv & 1) * 4] = wv;
            }
        }
        __syncthreads();

        if (it < myNt) {
            // ---- S^T = K @ Q^T ----
            f32x4 st[4] = {};
            __builtin_amdgcn_s_setprio(1);
            #pragma unroll
            for (int tt = 0; tt < 4; ++tt) {
                #pragma unroll
                for (int kk = 0; kk < 2; ++kk) {
                    short8 kf = *(const short8*)&K_lds[(tt * 16 + q) * 64 + ((4 * kk + g) ^ (q & 7)) * 8];
                    st[tt] = __builtin_amdgcn_mfma_f32_16x16x32_bf16(kf, qf[kk], st[tt], 0, 0, 0);
                }
            }
            __builtin_amdgcn_s_setprio(0);

            // ---- online softmax (16 lane-local + 2 shuffles) ----
            float mt = -1e30f;
            #pragma unroll
            for (int tt = 0; tt < 4; ++tt)
                #pragma unroll
                for (int j = 0; j < 4; ++j) {
                    float s = st[tt][j] * 0.125f;
                    int kvg = kv0 + tt * 16 + g * 4 + j;
                    s = (kvg <= qg) ? s : -1e30f;
                    st[tt][j] = s;
                    mt = fmaxf(mt, s);
                }
            mt = fmaxf(mt, __shfl_xor(mt, 16, 64));
            mt = fmaxf(mt, __shfl_xor(mt, 32, 64));
            float m_new = fmaxf(m_run, mt);
            float corr = __expf(m_run - m_new);
            float lsum = 0.f;
            #pragma unroll
            for (int tt = 0; tt < 4; ++tt)
                #pragma unroll
                for (int j = 0; j < 4; ++j) {
                    float p = __expf(st[tt][j] - m_new);
                    st[tt][j] = p;
                    lsum += p;
                }
            lsum += __shfl_xor(lsum, 16, 64);
            lsum += __shfl_xor(lsum, 32, 64);
            l_run = l_run * corr + lsum;
            m_run = m_new;

            // ---- P -> wave-private LDS (bf16), layout [q][kv] swizzled ----
            #pragma unroll
            for (int tt = 0; tt < 4; ++tt) {
                unsigned int lo = ((unsigned int)f2bf(st[tt][1]) << 16) | (unsigned int)f2bf(st[tt][0]);
                unsigned int hi = ((unsigned int)f2bf(st[tt][3]) << 16) | (unsigned int)f2bf(st[tt][2]);
                uint2 pk = make_uint2(lo, hi);
                *(uint2*)&P_lds[w * 1024 + q * 64 + ((2 * tt + (g >> 1)) ^ (q & 7)) * 8 + (g & 1) * 4] = pk;
            }

            // ---- rescale O ----
            #pragma unroll
            for (int j = 0; j < 4; ++j) {
                float cj = __shfl(corr, g * 4 + j, 64);
                #pragma unroll
                for (int dn = 0; dn < 4; ++dn)
                    oacc[dn][j] *= cj;
            }

            // ---- PV: O[16q][64d] += P @ V ----
            __builtin_amdgcn_s_setprio(1);
            #pragma unroll
            for (int kk = 0; kk < 2; ++kk) {
                short8 pf = *(const short8*)&P_lds[w * 1024 + q * 64 + ((4 * kk + g) ^ (q & 7)) * 8];
                #pragma unroll
                for (int dn = 0; dn < 4; ++dn) {
                    short8 vf = *(const short8*)&Vt_lds[(dn * 16 + q) * 64 + ((4 * kk + g) ^ (q & 7)) * 8];
                    oacc[dn] = __builtin_amdgcn_mfma_f32_16x16x32_bf16(pf, vf, oacc[dn], 0, 0, 0);
                }
            }
            __builtin_amdgcn_s_setprio(0);
        }
    }

    // ---- epilogue: normalize and store ----
    #pragma unroll
    for (int j = 0; j < 4; ++j) {
        float lj = __shfl(l_run, g * 4 + j, 64);
        float inv = 1.f / lj;
        int orow = q0 + wq4 * 16 + g * 4 + j;
        #pragma unroll
        for (int dn = 0; dn < 4; ++dn) {
            unsigned short* op = (unsigned short*)o;
            op[(size_t)(b * SS + orow) * DD + h * HSZ + dn * 16 + q] = f2bf(oacc[dn][j] * inv);
        }
    }
}

// ---------------- launch ----------------
extern "C" void kernel_launch(void* const* d_in, const int* in_sizes, int n_in,
                              void* d_out, int out_size, void* d_ws, size_t ws_size,
                              hipStream_t stream)
{
    const float* x      = (const float*)d_in[0];
    const float* wq     = (const float*)d_in[1];
    const float* wk     = (const float*)d_in[2];
    const float* wv     = (const float*)d_in[3];
    const float* proj_w = (const float*)d_in[4];
    const float* proj_b = (const float*)d_in[5];
    const float* ff1_w  = (const float*)d_in[6];
    const float* ff1_b  = (const float*)d_in[7];
    const float* ff2_w  = (const float*)d_in[8];
    const float* ff2_b  = (const float*)d_in[9];
    const float* ln1_g  = (const float*)d_in[10];
    const float* ln1_b  = (const float*)d_in[11];
    const float* ln2_g  = (const float*)d_in[12];
    const float* ln2_b  = (const float*)d_in[13];
    float* out = (float*)d_out;

    char* ws = (char*)d_ws;
    const size_t MB = 1ull << 20;
    __hip_bfloat16* h     = (__hip_bfloat16*)(ws);              // 16MB (h / h2)
    __hip_bfloat16* qkv   = (__hip_bfloat16*)(ws + 16 * MB);    // 48MB
    __hip_bfloat16* obuf  = (__hip_bfloat16*)(ws + 64 * MB);    // 16MB
    float*          x1    = (float*)(ws + 80 * MB);             // 32MB
    __hip_bfloat16* wqkvT = (__hip_bfloat16*)(ws + 112 * MB);   // 6MB
    __hip_bfloat16* projT = (__hip_bfloat16*)(ws + 118 * MB);   // 2MB
    __hip_bfloat16* ff1T  = (__hip_bfloat16*)(ws + 120 * MB);   // 8MB
    __hip_bfloat16* ff2T  = (__hip_bfloat16*)(ws + 128 * MB);   // 8MB
    __hip_bfloat16* f1    = (__hip_bfloat16*)(ws + 16 * MB);    // 64MB, aliases qkv+obuf (dead by then)

    const int ROWS = BB * SS;   // 8192

    pack_qkv_kernel<<<(3 * DD * DD) / 256, 256, 0, stream>>>(wq, wk, wv, wqkvT);
    pack_T_kernel<<<(DD * DD) / 256, 256, 0, stream>>>(proj_w, projT, DD, DD);
    pack_T_kernel<<<(DD * DFF) / 256, 256, 0, stream>>>(ff1_w, ff1T, DD, DFF);
    pack_T_kernel<<<(DFF * DD) / 256, 256, 0, stream>>>(ff2_w, ff2T, DFF, DD);

    ln_kernel<<<ROWS, 256, 0, stream>>>(x, ln1_g, ln1_b, h);
    gemm_kernel<false, false, false, false><<<dim3(3 * DD / 128, ROWS / 128), 256, 0, stream>>>(
        h, wqkvT, nullptr, nullptr, qkv, ROWS, 3 * DD, DD);
    attn_kernel<<<BB * HH * 16, 512, 0, stream>>>(qkv, obuf);
    gemm_kernel<true, false, true, true><<<dim3(DD / 128, ROWS / 128), 256, 0, stream>>>(
        obuf, projT, proj_b, x, x1, ROWS, DD, DD);
    ln_kernel<<<ROWS, 256, 0, stream>>>(x1, ln2_g, ln2_b, h);
    gemm_kernel<true, true, false, false><<<dim3(DFF / 128, ROWS / 128), 256, 0, stream>>>(
        h, ff1T, ff1_b, nullptr, f1, ROWS, DFF, DD);
    gemm_kernel<true, false, true, true><<<dim3(DD / 128, ROWS / 128), 256, 0, stream>>>(
        f1, ff2T, ff2_b, x1, out, ROWS, DD, DFF);
}

// Round 4
// 486.127 us; speedup vs baseline: 13.1721x; 1.0570x over previous
//
#include <hip/hip_runtime.h>
#include <hip/hip_bf16.h>

#define BB 4
#define SS 2048
#define DD 1024
#define HH 16
#define HSZ 64
#define DFF 4096

typedef short short8 __attribute__((ext_vector_type(8)));
typedef float f32x4 __attribute__((ext_vector_type(4)));
typedef unsigned short us4 __attribute__((ext_vector_type(4)));

#define AS1 __attribute__((address_space(1)))
#define AS3 __attribute__((address_space(3)))

__device__ __forceinline__ unsigned short f2bf(float f) {
    return __bfloat16_as_ushort(__float2bfloat16(f));
}

// ---------------- weight repack kernels ----------------
__global__ __launch_bounds__(256) void pack_qkv_kernel(
    const float* __restrict__ wq, const float* __restrict__ wk,
    const float* __restrict__ wv, __hip_bfloat16* __restrict__ out)
{
    int id = blockIdx.x * 256 + threadIdx.x;      // over 3072*1024
    int n = id >> 10;
    int k = id & 1023;
    int sel = n >> 10;
    int hn = n & 1023;
    int h = hn >> 6, e = hn & 63;
    const float* src = (sel == 0) ? wq : (sel == 1) ? wk : wv;
    out[id] = __float2bfloat16(src[(size_t)h * (DD * HSZ) + (size_t)k * HSZ + e]);
}

__global__ __launch_bounds__(256) void pack_T_kernel(
    const float* __restrict__ in, __hip_bfloat16* __restrict__ out, int K, int N)
{
    int id = blockIdx.x * 256 + threadIdx.x;      // over N*K
    int n = id / K;
    int k = id - n * K;
    out[id] = __float2bfloat16(in[(size_t)k * N + n]);
}

// ---------------- layernorm ----------------
__global__ __launch_bounds__(256) void ln_kernel(
    const float* __restrict__ x, const float* __restrict__ g,
    const float* __restrict__ b, __hip_bfloat16* __restrict__ out)
{
    int row = blockIdx.x;
    int t = threadIdx.x;
    const float4* xr = (const float4*)(x + (size_t)row * DD);
    float4 v = xr[t];
    float s = v.x + v.y + v.z + v.w;
    float ss = v.x * v.x + v.y * v.y + v.z * v.z + v.w * v.w;
    #pragma unroll
    for (int off = 32; off; off >>= 1) {
        s += __shfl_xor(s, off, 64);
        ss += __shfl_xor(ss, off, 64);
    }
    __shared__ float red[8];
    int w = t >> 6, lane = t & 63;
    if (lane == 0) { red[w] = s; red[4 + w] = ss; }
    __syncthreads();
    s = red[0] + red[1] + red[2] + red[3];
    ss = red[4] + red[5] + red[6] + red[7];
    float mu = s * (1.f / DD);
    float var = ss * (1.f / DD) - mu * mu;
    float rs = rsqrtf(var + 1e-5f);
    float4 gv = ((const float4*)g)[t];
    float4 bv = ((const float4*)b)[t];
    ushort4 pk = make_ushort4(
        f2bf((v.x - mu) * rs * gv.x + bv.x),
        f2bf((v.y - mu) * rs * gv.y + bv.y),
        f2bf((v.z - mu) * rs * gv.z + bv.z),
        f2bf((v.w - mu) * rs * gv.w + bv.w));
    *(ushort4*)((unsigned short*)out + (size_t)row * DD + t * 4) = pk;
}

// ---------------- bf16 MFMA GEMM: C[M,N] = A[M,K] @ BT[N,K]^T ----------------
// 128x128 tile, BK=32. 1D grid with XCD-chunked swizzle (nwg % 8 == 0).
template<bool BIAS, bool RELU, bool RES, bool OUTF32>
__global__ __launch_bounds__(256) void gemm_kernel(
    const __hip_bfloat16* __restrict__ A, const __hip_bfloat16* __restrict__ BT,
    const float* __restrict__ bias, const float* __restrict__ res,
    void* __restrict__ Cout, int M, int N, int K, int nbx)
{
    __shared__ uint4 As[512];   // frag (r,kb) at slot r*4 + (kb ^ ((r>>1)&3))
    __shared__ uint4 Bs[512];
    const int t = threadIdx.x;
    const int lane = t & 63, w = t >> 6;
    // XCD-aware chunked swizzle
    const int nwg = gridDim.x;
    const int cpx = nwg >> 3;
    const int wg = blockIdx.x;
    const int swz = (wg & 7) * cpx + (wg >> 3);
    const int bx = swz % nbx, by = swz / nbx;
    const int row0 = by * 128, col0 = bx * 128;
    const int wr = (w >> 1) * 64, wc = (w & 1) * 64;
    const int lr = lane & 15, kb = lane >> 4;
    f32x4 acc[4][4] = {};

    for (int k0 = 0; k0 < K; k0 += 32) {
        __syncthreads();
        #pragma unroll
        for (int j = 0; j < 2; ++j) {
            int s = w * 128 + j * 64 + lane;
            int r = s >> 2;
            int fkb = (s & 3) ^ ((r >> 1) & 3);
            const __hip_bfloat16* asrc = A + (size_t)(row0 + r) * K + k0 + fkb * 8;
            const __hip_bfloat16* bsrc = BT + (size_t)(col0 + r) * K + k0 + fkb * 8;
            __builtin_amdgcn_global_load_lds((const AS1 void*)asrc, (AS3 void*)&As[w * 128 + j * 64], 16, 0, 0);
            __builtin_amdgcn_global_load_lds((const AS1 void*)bsrc, (AS3 void*)&Bs[w * 128 + j * 64], 16, 0, 0);
        }
        __syncthreads();
        short8 af[4], bfr[4];
        #pragma unroll
        for (int m = 0; m < 4; ++m) {
            int r = wr + m * 16 + lr;
            af[m] = *(const short8*)&As[r * 4 + (kb ^ ((r >> 1) & 3))];
        }
        #pragma unroll
        for (int n = 0; n < 4; ++n) {
            int c = wc + n * 16 + lr;
            bfr[n] = *(const short8*)&Bs[c * 4 + (kb ^ ((c >> 1) & 3))];
        }
        #pragma unroll
        for (int m = 0; m < 4; ++m)
            #pragma unroll
            for (int n = 0; n < 4; ++n)
                acc[m][n] = __builtin_amdgcn_mfma_f32_16x16x32_bf16(af[m], bfr[n], acc[m][n], 0, 0, 0);
    }

    #pragma unroll
    for (int m = 0; m < 4; ++m) {
        #pragma unroll
        for (int j = 0; j < 4; ++j) {
            int rr = row0 + wr + m * 16 + (lane >> 4) * 4 + j;
            #pragma unroll
            for (int n = 0; n < 4; ++n) {
                int cc = col0 + wc + n * 16 + lr;
                float vv = acc[m][n][j];
                if (BIAS) vv += bias[cc];
                if (RELU) vv = fmaxf(vv, 0.f);
                if (RES) vv += res[(size_t)rr * N + cc];
                if (OUTF32) ((float*)Cout)[(size_t)rr * N + cc] = vv;
                else ((__hip_bfloat16*)Cout)[(size_t)rr * N + cc] = __float2bfloat16(vv);
            }
        }
    }
}

// ---------------- MFMA flash attention, uniform work split ----------------
// Block = (b,h,pq): 8 waves. Group0 (waves 0-3): q-tile pq; Group1 (waves 4-7): q-tile 31-pq.
// Group1 handles kv tiles [0..15] of its tile. Group0 handles its own tile's kv [0..pq],
// writes that output, then processes kv tiles [16..31-pq] of group1's tile (using its Q),
// and the partial states merge via LDS at the end. Every block: exactly 17 iterations.
__device__ __forceinline__ void stage_kv(
    const unsigned short* __restrict__ qkvu, size_t rowbase, int h, int kv0, int tl,
    unsigned short* __restrict__ Kb, unsigned short* __restrict__ Vb)
{
    // K: [64 kv][64 d], chunk swizzle ^= kv&7 (conflict-free per 16-lane quarter)
    {
        int kv = tl >> 2, c = tl & 3;
        const unsigned short* src = qkvu + rowbase + (size_t)(kv0 + kv) * 3072 + DD + h * HSZ + c * 16;
        uint4 v0 = *(const uint4*)src;
        uint4 v1 = *(const uint4*)(src + 8);
        int sw = kv & 7;
        *(uint4*)&Kb[kv * 64 + ((2 * c) ^ sw) * 8] = v0;
        *(uint4*)&Kb[kv * 64 + ((2 * c + 1) ^ sw) * 8] = v1;
    }
    // V transposed: [64 d][64 kv]; thread map chosen so (chunk,sub) spread within quarters
    {
        int bkv = ((tl >> 6) << 2) | (tl & 3);
        int bd = (tl >> 2) & 15;
        const unsigned short* src = qkvu + rowbase + (size_t)(kv0 + bkv * 4) * 3072 + 2 * DD + h * HSZ + bd * 4;
        us4 r0 = *(const us4*)src;
        us4 r1 = *(const us4*)(src + 3072);
        us4 r2 = *(const us4*)(src + 2 * 3072);
        us4 r3 = *(const us4*)(src + 3 * 3072);
        #pragma unroll
        for (int cc = 0; cc < 4; ++cc) {
            int d = bd * 4 + cc;
            us4 wv = { r0[cc], r1[cc], r2[cc], r3[cc] };
            *(us4*)&Vb[d * 64 + (((bkv >> 1) ^ (d & 7)) * 8) + (bkv & 1) * 4] = wv;
        }
    }
}

__device__ __forceinline__ void flash_tile(
    const unsigned short* __restrict__ Kb, const unsigned short* __restrict__ Vb,
    unsigned short* __restrict__ Pw, const short8* qfc, int qgc, int kv0, int q, int g,
    float& m_run, float& l_run, f32x4* oacc)
{
    f32x4 st[4] = {};
    __builtin_amdgcn_s_setprio(1);
    #pragma unroll
    for (int tt = 0; tt < 4; ++tt) {
        #pragma unroll
        for (int kk = 0; kk < 2; ++kk) {
            short8 kf = *(const short8*)&Kb[(tt * 16 + q) * 64 + ((4 * kk + g) ^ (q & 7)) * 8];
            st[tt] = __builtin_amdgcn_mfma_f32_16x16x32_bf16(kf, qfc[kk], st[tt], 0, 0, 0);
        }
    }
    __builtin_amdgcn_s_setprio(0);

    float mt = -1e30f;
    #pragma unroll
    for (int tt = 0; tt < 4; ++tt)
        #pragma unroll
        for (int j = 0; j < 4; ++j) {
            float s = st[tt][j] * 0.125f;
            int kvg = kv0 + tt * 16 + g * 4 + j;
            s = (kvg <= qgc) ? s : -1e30f;
            st[tt][j] = s;
            mt = fmaxf(mt, s);
        }
    mt = fmaxf(mt, __shfl_xor(mt, 16, 64));
    mt = fmaxf(mt, __shfl_xor(mt, 32, 64));
    float m_new = fmaxf(m_run, mt);
    float corr = __expf(m_run - m_new);
    float lsum = 0.f;
    #pragma unroll
    for (int tt = 0; tt < 4; ++tt)
        #pragma unroll
        for (int j = 0; j < 4; ++j) {
            float p = __expf(st[tt][j] - m_new);
            st[tt][j] = p;
            lsum += p;
        }
    lsum += __shfl_xor(lsum, 16, 64);
    lsum += __shfl_xor(lsum, 32, 64);
    l_run = l_run * corr + lsum;
    m_run = m_new;

    #pragma unroll
    for (int tt = 0; tt < 4; ++tt) {
        unsigned int lo = ((unsigned int)f2bf(st[tt][1]) << 16) | (unsigned int)f2bf(st[tt][0]);
        unsigned int hi = ((unsigned int)f2bf(st[tt][3]) << 16) | (unsigned int)f2bf(st[tt][2]);
        uint2 pk = make_uint2(lo, hi);
        *(uint2*)&Pw[q * 64 + ((2 * tt + (g >> 1)) ^ (q & 7)) * 8 + (g & 1) * 4] = pk;
    }

    #pragma unroll
    for (int j = 0; j < 4; ++j) {
        float cj = __shfl(corr, g * 4 + j, 64);
        #pragma unroll
        for (int dn = 0; dn < 4; ++dn)
            oacc[dn][j] *= cj;
    }

    __builtin_amdgcn_s_setprio(1);
    #pragma unroll
    for (int kk = 0; kk < 2; ++kk) {
        short8 pf = *(const short8*)&Pw[q * 64 + ((4 * kk + g) ^ (q & 7)) * 8];
        #pragma unroll
        for (int dn = 0; dn < 4; ++dn) {
            short8 vf = *(const short8*)&Vb[(dn * 16 + q) * 64 + ((4 * kk + g) ^ (q & 7)) * 8];
            oacc[dn] = __builtin_amdgcn_mfma_f32_16x16x32_bf16(pf, vf, oacc[dn], 0, 0, 0);
        }
    }
    __builtin_amdgcn_s_setprio(0);
}

__global__ __launch_bounds__(512) void attn_kernel(
    const __hip_bfloat16* __restrict__ qkv, __hip_bfloat16* __restrict__ o)
{
    __shared__ unsigned short K_lds[2][64 * 64];
    __shared__ unsigned short Vt_lds[2][64 * 64];
    __shared__ unsigned short P_lds[8 * 1024];

    const int t = threadIdx.x;
    const int lane = t & 63, w = t >> 6;
    const int grp = w >> 2, wq4 = w & 3, tl = t & 255;
    const int q = lane & 15, g = lane >> 4;
    const int pq = blockIdx.x & 15;
    const int h = (blockIdx.x >> 4) & 15;
    const int b = blockIdx.x >> 8;
    const int qtA = pq, qtB = 31 - pq;
    const int qt1 = grp ? qtB : qtA;
    const unsigned short* qkvu = (const unsigned short*)qkv;
    const size_t rowbase = (size_t)(b * SS) * 3072;
    unsigned short* Kb = K_lds[grp];
    unsigned short* Vb = Vt_lds[grp];
    unsigned short* Pw = &P_lds[w * 1024];
    unsigned short* op = (unsigned short*)o;

    // current Q fragments (B-operand: col=q, k=g*8+i, +32 per kk)
    int qgc = qt1 * 64 + wq4 * 16 + q;
    short8 qfc[2];
    #pragma unroll
    for (int kk = 0; kk < 2; ++kk)
        qfc[kk] = *(const short8*)(qkvu + rowbase + (size_t)qgc * 3072 + h * HSZ + kk * 32 + g * 8);

    f32x4 oacc[4] = {};
    float m_run = -1e30f, l_run = 0.f;

    // ---- loop1: tiles 0..pq (both groups) ----
    for (int it = 0; it <= pq; ++it) {
        __syncthreads();
        stage_kv(qkvu, rowbase, h, it * 64, tl, Kb, Vb);
        __syncthreads();
        flash_tile(Kb, Vb, Pw, qfc, qgc, it * 64, q, g, m_run, l_run, oacc);
    }

    // ---- group0: write tile-pq output, switch to helping with tile qtB ----
    if (grp == 0) {
        #pragma unroll
        for (int j = 0; j < 4; ++j) {
            float lj = __shfl(l_run, g * 4 + j, 64);
            float inv = 1.f / lj;
            int orow = qtA * 64 + wq4 * 16 + g * 4 + j;
            #pragma unroll
            for (int dn = 0; dn < 4; ++dn)
                op[(size_t)(b * SS + orow) * DD + h * HSZ + dn * 16 + q] = f2bf(oacc[dn][j] * inv);
        }
        qgc = qtB * 64 + wq4 * 16 + q;
        #pragma unroll
        for (int kk = 0; kk < 2; ++kk)
            qfc[kk] = *(const short8*)(qkvu + rowbase + (size_t)qgc * 3072 + h * HSZ + kk * 32 + g * 8);
        m_run = -1e30f; l_run = 0.f;
        #pragma unroll
        for (int dn = 0; dn < 4; ++dn) oacc[dn] = f32x4{0.f, 0.f, 0.f, 0.f};
    }

    // ---- loop2: group0 tiles 16..31-pq (for tile qtB); group1 tiles pq+1..15 ----
    for (int it2 = 0; it2 < 16 - pq; ++it2) {
        int tile = grp ? (pq + 1 + it2) : (16 + it2);
        bool active = grp ? (tile <= 15) : true;
        __syncthreads();
        if (active) stage_kv(qkvu, rowbase, h, tile * 64, tl, Kb, Vb);
        __syncthreads();
        if (active) flash_tile(Kb, Vb, Pw, qfc, qgc, tile * 64, q, g, m_run, l_run, oacc);
    }

    // ---- merge partial states for tile qtB ----
    __syncthreads();
    float* obuf = (float*)K_lds;     // 16KB: 4 waves x 1024 floats
    float* mlbuf = (float*)P_lds;    // 4 waves x 32 floats
    if (grp == 0) {
        #pragma unroll
        for (int dn = 0; dn < 4; ++dn)
            #pragma unroll
            for (int j = 0; j < 4; ++j)
                obuf[wq4 * 1024 + lane * 16 + dn * 4 + j] = oacc[dn][j];
        if (g == 0) { mlbuf[wq4 * 32 + q] = m_run; mlbuf[wq4 * 32 + 16 + q] = l_run; }
    }
    __syncthreads();
    if (grp == 1) {
        float mA = mlbuf[wq4 * 32 + q];
        float lA = mlbuf[wq4 * 32 + 16 + q];
        float mM = fmaxf(m_run, mA);
        float sB = __expf(m_run - mM);
        float sA = __expf(mA - mM);
        float lM = l_run * sB + lA * sA;
        #pragma unroll
        for (int j = 0; j < 4; ++j) {
            float sBj = __shfl(sB, g * 4 + j, 64);
            float sAj = __shfl(sA, g * 4 + j, 64);
            float lMj = __shfl(lM, g * 4 + j, 64);
            float inv = 1.f / lMj;
            int orow = qtB * 64 + wq4 * 16 + g * 4 + j;
            #pragma unroll
            for (int dn = 0; dn < 4; ++dn) {
                float oA = obuf[wq4 * 1024 + lane * 16 + dn * 4 + j];
                float vv = (oacc[dn][j] * sBj + oA * sAj) * inv;
                op[(size_t)(b * SS + orow) * DD + h * HSZ + dn * 16 + q] = f2bf(vv);
            }
        }
    }
}

// ---------------- launch ----------------
extern "C" void kernel_launch(void* const* d_in, const int* in_sizes, int n_in,
                              void* d_out, int out_size, void* d_ws, size_t ws_size,
                              hipStream_t stream)
{
    const float* x      = (const float*)d_in[0];
    const float* wq     = (const float*)d_in[1];
    const float* wk     = (const float*)d_in[2];
    const float* wv     = (const float*)d_in[3];
    const float* proj_w = (const float*)d_in[4];
    const float* proj_b = (const float*)d_in[5];
    const float* ff1_w  = (const float*)d_in[6];
    const float* ff1_b  = (const float*)d_in[7];
    const float* ff2_w  = (const float*)d_in[8];
    const float* ff2_b  = (const float*)d_in[9];
    const float* ln1_g  = (const float*)d_in[10];
    const float* ln1_b  = (const float*)d_in[11];
    const float* ln2_g  = (const float*)d_in[12];
    const float* ln2_b  = (const float*)d_in[13];
    float* out = (float*)d_out;

    char* ws = (char*)d_ws;
    const size_t MB = 1ull << 20;
    __hip_bfloat16* h     = (__hip_bfloat16*)(ws);              // 16MB (h / h2)
    __hip_bfloat16* qkv   = (__hip_bfloat16*)(ws + 16 * MB);    // 48MB
    __hip_bfloat16* obuf  = (__hip_bfloat16*)(ws + 64 * MB);    // 16MB
    float*          x1    = (float*)(ws + 80 * MB);             // 32MB
    __hip_bfloat16* wqkvT = (__hip_bfloat16*)(ws + 112 * MB);   // 6MB
    __hip_bfloat16* projT = (__hip_bfloat16*)(ws + 118 * MB);   // 2MB
    __hip_bfloat16* ff1T  = (__hip_bfloat16*)(ws + 120 * MB);   // 8MB
    __hip_bfloat16* ff2T  = (__hip_bfloat16*)(ws + 128 * MB);   // 8MB
    __hip_bfloat16* f1    = (__hip_bfloat16*)(ws + 16 * MB);    // 64MB, aliases qkv+obuf (dead by then)

    const int ROWS = BB * SS;   // 8192

    pack_qkv_kernel<<<(3 * DD * DD) / 256, 256, 0, stream>>>(wq, wk, wv, wqkvT);
    pack_T_kernel<<<(DD * DD) / 256, 256, 0, stream>>>(proj_w, projT, DD, DD);
    pack_T_kernel<<<(DD * DFF) / 256, 256, 0, stream>>>(ff1_w, ff1T, DD, DFF);
    pack_T_kernel<<<(DFF * DD) / 256, 256, 0, stream>>>(ff2_w, ff2T, DFF, DD);

    ln_kernel<<<ROWS, 256, 0, stream>>>(x, ln1_g, ln1_b, h);
    gemm_kernel<false, false, false, false><<<(3 * DD / 128) * (ROWS / 128), 256, 0, stream>>>(
        h, wqkvT, nullptr, nullptr, qkv, ROWS, 3 * DD, DD, 3 * DD / 128);
    attn_kernel<<<BB * HH * 16, 512, 0, stream>>>(qkv, obuf);
    gemm_kernel<true, false, true, true><<<(DD / 128) * (ROWS / 128), 256, 0, stream>>>(
        obuf, projT, proj_b, x, x1, ROWS, DD, DD, DD / 128);
    ln_kernel<<<ROWS, 256, 0, stream>>>(x1, ln2_g, ln2_b, h);
    gemm_kernel<true, true, false, false><<<(DFF / 128) * (ROWS / 128), 256, 0, stream>>>(
        h, ff1T, ff1_b, nullptr, f1, ROWS, DFF, DD, DFF / 128);
    gemm_kernel<true, false, true, true><<<(DD / 128) * (ROWS / 128), 256, 0, stream>>>(
        f1, ff2T, ff2_b, x1, out, ROWS, DD, DFF, DD / 128);
}

// Round 5
// 441.907 us; speedup vs baseline: 14.4902x; 1.1001x over previous
//
#include <hip/hip_runtime.h>
#include <hip/hip_bf16.h>

#define BB 4
#define SS 2048
#define DD 1024
#define HH 16
#define HSZ 64
#define DFF 4096

typedef short short8 __attribute__((ext_vector_type(8)));
typedef float f32x4 __attribute__((ext_vector_type(4)));
typedef unsigned short us4 __attribute__((ext_vector_type(4)));

#define AS1 __attribute__((address_space(1)))
#define AS3 __attribute__((address_space(3)))

__device__ __forceinline__ unsigned short f2bf(float f) {
    return __bfloat16_as_ushort(__float2bfloat16(f));
}

// ---------------- weight repack kernels ----------------
__global__ __launch_bounds__(256) void pack_qkv_kernel(
    const float* __restrict__ wq, const float* __restrict__ wk,
    const float* __restrict__ wv, __hip_bfloat16* __restrict__ out)
{
    int id = blockIdx.x * 256 + threadIdx.x;      // over 3072*1024
    int n = id >> 10;
    int k = id & 1023;
    int sel = n >> 10;
    int hn = n & 1023;
    int h = hn >> 6, e = hn & 63;
    const float* src = (sel == 0) ? wq : (sel == 1) ? wk : wv;
    out[id] = __float2bfloat16(src[(size_t)h * (DD * HSZ) + (size_t)k * HSZ + e]);
}

__global__ __launch_bounds__(256) void pack_T_kernel(
    const float* __restrict__ in, __hip_bfloat16* __restrict__ out, int K, int N)
{
    int id = blockIdx.x * 256 + threadIdx.x;      // over N*K
    int n = id / K;
    int k = id - n * K;
    out[id] = __float2bfloat16(in[(size_t)k * N + n]);
}

// ---------------- layernorm ----------------
__global__ __launch_bounds__(256) void ln_kernel(
    const float* __restrict__ x, const float* __restrict__ g,
    const float* __restrict__ b, __hip_bfloat16* __restrict__ out)
{
    int row = blockIdx.x;
    int t = threadIdx.x;
    const float4* xr = (const float4*)(x + (size_t)row * DD);
    float4 v = xr[t];
    float s = v.x + v.y + v.z + v.w;
    float ss = v.x * v.x + v.y * v.y + v.z * v.z + v.w * v.w;
    #pragma unroll
    for (int off = 32; off; off >>= 1) {
        s += __shfl_xor(s, off, 64);
        ss += __shfl_xor(ss, off, 64);
    }
    __shared__ float red[8];
    int w = t >> 6, lane = t & 63;
    if (lane == 0) { red[w] = s; red[4 + w] = ss; }
    __syncthreads();
    s = red[0] + red[1] + red[2] + red[3];
    ss = red[4] + red[5] + red[6] + red[7];
    float mu = s * (1.f / DD);
    float var = ss * (1.f / DD) - mu * mu;
    float rs = rsqrtf(var + 1e-5f);
    float4 gv = ((const float4*)g)[t];
    float4 bv = ((const float4*)b)[t];
    ushort4 pk = make_ushort4(
        f2bf((v.x - mu) * rs * gv.x + bv.x),
        f2bf((v.y - mu) * rs * gv.y + bv.y),
        f2bf((v.z - mu) * rs * gv.z + bv.z),
        f2bf((v.w - mu) * rs * gv.w + bv.w));
    *(ushort4*)((unsigned short*)out + (size_t)row * DD + t * 4) = pk;
}

// ---------------- bf16 MFMA GEMM: C[M,N] = A[M,K] @ BT[N,K]^T ----------------
// 256xBN tile, BK=64, 8 waves (512 thr), double-buffered LDS + counted vmcnt.
// LDS fragment-slot layout: slot(r,kb) = r*8 + (kb ^ (r&7)); linear gload_lds dest
// with inverse-swizzled global source. Never drains vmcnt to 0 in the main loop.
template<int BN, bool BIAS, bool RELU, bool RES, bool OUTF32>
__global__ __launch_bounds__(512) void gemm_kernel(
    const __hip_bfloat16* __restrict__ A, const __hip_bfloat16* __restrict__ BT,
    const float* __restrict__ bias, const float* __restrict__ res,
    void* __restrict__ Cout, int M, int N, int K, int nbx)
{
    constexpr int WN = (BN == 256) ? 4 : 2;       // wave grid: 2x4 or 4x2
    constexpr int MREP = (BN == 256) ? 8 : 4;     // 16-row frags per wave
    constexpr int BLOADS = BN / 64;               // B gload_lds per thread per tile
    __shared__ uint4 As[2][2048];                 // 256 rows x 8 chunks
    __shared__ uint4 Bs[2][BN * 8];

    const int t = threadIdx.x;
    const int lane = t & 63, w = t >> 6;
    const int lr = lane & 15, g = lane >> 4;
    const int nwg = gridDim.x;
    const int cpx = nwg >> 3;
    const int wg = blockIdx.x;
    const int swz = (wg & 7) * cpx + (wg >> 3);   // XCD-chunked swizzle
    const int bx = swz % nbx, by = swz / nbx;
    const int row0 = by * 256, col0 = bx * BN;
    const int wr = (w / WN) * (MREP * 16), wc = (w % WN) * 64;

    f32x4 acc[MREP][4] = {};
    const int NT = K >> 6;

    auto stage = [&](int buf, int k0) {
        #pragma unroll
        for (int j = 0; j < 4; ++j) {
            int s = j * 512 + t;
            int r = s >> 3;
            int kb = (s & 7) ^ (r & 7);
            const __hip_bfloat16* src = A + (size_t)(row0 + r) * K + k0 + kb * 8;
            __builtin_amdgcn_global_load_lds((const AS1 void*)src,
                (AS3 void*)(&As[buf][j * 512 + (t & ~63)]), 16, 0, 0);
        }
        #pragma unroll
        for (int j = 0; j < BLOADS; ++j) {
            int s = j * 512 + t;
            int r = s >> 3;
            int kb = (s & 7) ^ (r & 7);
            const __hip_bfloat16* src = BT + (size_t)(col0 + r) * K + k0 + kb * 8;
            __builtin_amdgcn_global_load_lds((const AS1 void*)src,
                (AS3 void*)(&Bs[buf][j * 512 + (t & ~63)]), 16, 0, 0);
        }
    };

    auto compute = [&](int buf) {
        short8 bf[4][2];
        #pragma unroll
        for (int n = 0; n < 4; ++n) {
            int c = wc + n * 16 + lr;
            #pragma unroll
            for (int kk = 0; kk < 2; ++kk)
                bf[n][kk] = *(const short8*)&Bs[buf][c * 8 + ((kk * 4 + g) ^ (c & 7))];
        }
        #pragma unroll
        for (int ph = 0; ph < MREP / 2; ++ph) {
            short8 af[2][2];
            #pragma unroll
            for (int m2 = 0; m2 < 2; ++m2) {
                int r = wr + ph * 32 + m2 * 16 + lr;
                #pragma unroll
                for (int kk = 0; kk < 2; ++kk)
                    af[m2][kk] = *(const short8*)&As[buf][r * 8 + ((kk * 4 + g) ^ (r & 7))];
            }
            __builtin_amdgcn_s_setprio(1);
            #pragma unroll
            for (int m2 = 0; m2 < 2; ++m2)
                #pragma unroll
                for (int n = 0; n < 4; ++n)
                    #pragma unroll
                    for (int kk = 0; kk < 2; ++kk)
                        acc[ph * 2 + m2][n] = __builtin_amdgcn_mfma_f32_16x16x32_bf16(
                            af[m2][kk], bf[n][kk], acc[ph * 2 + m2][n], 0, 0, 0);
            __builtin_amdgcn_s_setprio(0);
        }
    };

    stage(0, 0);
    int cur = 0;
    for (int tt = 0; tt < NT - 1; ++tt) {
        stage(cur ^ 1, (tt + 1) * 64);            // next tile's loads: stay in flight
        if constexpr (BN == 256) asm volatile("s_waitcnt vmcnt(8)" ::: "memory");
        else                     asm volatile("s_waitcnt vmcnt(6)" ::: "memory");
        __builtin_amdgcn_s_barrier();             // tile tt fully staged (all waves)
        compute(cur);
        __builtin_amdgcn_sched_barrier(0);        // pin MFMA/ds_read above barrier
        __builtin_amdgcn_s_barrier();             // buf[cur] free for next stage
        cur ^= 1;
    }
    asm volatile("s_waitcnt vmcnt(0)" ::: "memory");
    __builtin_amdgcn_s_barrier();
    compute(cur);

    #pragma unroll
    for (int mi = 0; mi < MREP; ++mi) {
        #pragma unroll
        for (int j = 0; j < 4; ++j) {
            int rr = row0 + wr + mi * 16 + g * 4 + j;
            #pragma unroll
            for (int n = 0; n < 4; ++n) {
                int cc = col0 + wc + n * 16 + lr;
                float vv = acc[mi][n][j];
                if (BIAS) vv += bias[cc];
                if (RELU) vv = fmaxf(vv, 0.f);
                if (RES) vv += res[(size_t)rr * N + cc];
                if (OUTF32) ((float*)Cout)[(size_t)rr * N + cc] = vv;
                else ((__hip_bfloat16*)Cout)[(size_t)rr * N + cc] = __float2bfloat16(vv);
            }
        }
    }
}

// ---------------- MFMA flash attention, uniform work split ----------------
__device__ __forceinline__ void stage_kv(
    const unsigned short* __restrict__ qkvu, size_t rowbase, int h, int kv0, int tl,
    unsigned short* __restrict__ Kb, unsigned short* __restrict__ Vb)
{
    {
        int kv = tl >> 2, c = tl & 3;
        const unsigned short* src = qkvu + rowbase + (size_t)(kv0 + kv) * 3072 + DD + h * HSZ + c * 16;
        uint4 v0 = *(const uint4*)src;
        uint4 v1 = *(const uint4*)(src + 8);
        int sw = kv & 7;
        *(uint4*)&Kb[kv * 64 + ((2 * c) ^ sw) * 8] = v0;
        *(uint4*)&Kb[kv * 64 + ((2 * c + 1) ^ sw) * 8] = v1;
    }
    {
        int bkv = ((tl >> 6) << 2) | (tl & 3);
        int bd = (tl >> 2) & 15;
        const unsigned short* src = qkvu + rowbase + (size_t)(kv0 + bkv * 4) * 3072 + 2 * DD + h * HSZ + bd * 4;
        us4 r0 = *(const us4*)src;
        us4 r1 = *(const us4*)(src + 3072);
        us4 r2 = *(const us4*)(src + 2 * 3072);
        us4 r3 = *(const us4*)(src + 3 * 3072);
        #pragma unroll
        for (int cc = 0; cc < 4; ++cc) {
            int d = bd * 4 + cc;
            us4 wv = { r0[cc], r1[cc], r2[cc], r3[cc] };
            *(us4*)&Vb[d * 64 + (((bkv >> 1) ^ (d & 7)) * 8) + (bkv & 1) * 4] = wv;
        }
    }
}

__device__ __forceinline__ void flash_tile(
    const unsigned short* __restrict__ Kb, const unsigned short* __restrict__ Vb,
    unsigned short* __restrict__ Pw, const short8* qfc, int qgc, int kv0, int q, int g,
    float& m_run, float& l_run, f32x4* oacc)
{
    f32x4 st[4] = {};
    __builtin_amdgcn_s_setprio(1);
    #pragma unroll
    for (int tt = 0; tt < 4; ++tt) {
        #pragma unroll
        for (int kk = 0; kk < 2; ++kk) {
            short8 kf = *(const short8*)&Kb[(tt * 16 + q) * 64 + ((4 * kk + g) ^ (q & 7)) * 8];
            st[tt] = __builtin_amdgcn_mfma_f32_16x16x32_bf16(kf, qfc[kk], st[tt], 0, 0, 0);
        }
    }
    __builtin_amdgcn_s_setprio(0);

    float mt = -1e30f;
    #pragma unroll
    for (int tt = 0; tt < 4; ++tt)
        #pragma unroll
        for (int j = 0; j < 4; ++j) {
            float s = st[tt][j] * 0.125f;
            int kvg = kv0 + tt * 16 + g * 4 + j;
            s = (kvg <= qgc) ? s : -1e30f;
            st[tt][j] = s;
            mt = fmaxf(mt, s);
        }
    mt = fmaxf(mt, __shfl_xor(mt, 16, 64));
    mt = fmaxf(mt, __shfl_xor(mt, 32, 64));
    float m_new = fmaxf(m_run, mt);
    float corr = __expf(m_run - m_new);
    float lsum = 0.f;
    #pragma unroll
    for (int tt = 0; tt < 4; ++tt)
        #pragma unroll
        for (int j = 0; j < 4; ++j) {
            float p = __expf(st[tt][j] - m_new);
            st[tt][j] = p;
            lsum += p;
        }
    lsum += __shfl_xor(lsum, 16, 64);
    lsum += __shfl_xor(lsum, 32, 64);
    l_run = l_run * corr + lsum;
    m_run = m_new;

    #pragma unroll
    for (int tt = 0; tt < 4; ++tt) {
        unsigned int lo = ((unsigned int)f2bf(st[tt][1]) << 16) | (unsigned int)f2bf(st[tt][0]);
        unsigned int hi = ((unsigned int)f2bf(st[tt][3]) << 16) | (unsigned int)f2bf(st[tt][2]);
        uint2 pk = make_uint2(lo, hi);
        *(uint2*)&Pw[q * 64 + ((2 * tt + (g >> 1)) ^ (q & 7)) * 8 + (g & 1) * 4] = pk;
    }

    #pragma unroll
    for (int j = 0; j < 4; ++j) {
        float cj = __shfl(corr, g * 4 + j, 64);
        #pragma unroll
        for (int dn = 0; dn < 4; ++dn)
            oacc[dn][j] *= cj;
    }

    __builtin_amdgcn_s_setprio(1);
    #pragma unroll
    for (int kk = 0; kk < 2; ++kk) {
        short8 pf = *(const short8*)&Pw[q * 64 + ((4 * kk + g) ^ (q & 7)) * 8];
        #pragma unroll
        for (int dn = 0; dn < 4; ++dn) {
            short8 vf = *(const short8*)&Vb[(dn * 16 + q) * 64 + ((4 * kk + g) ^ (q & 7)) * 8];
            oacc[dn] = __builtin_amdgcn_mfma_f32_16x16x32_bf16(pf, vf, oacc[dn], 0, 0, 0);
        }
    }
    __builtin_amdgcn_s_setprio(0);
}

__global__ __launch_bounds__(512) void attn_kernel(
    const __hip_bfloat16* __restrict__ qkv, __hip_bfloat16* __restrict__ o)
{
    __shared__ unsigned short K_lds[2][64 * 64];
    __shared__ unsigned short Vt_lds[2][64 * 64];
    __shared__ unsigned short P_lds[8 * 1024];

    const int t = threadIdx.x;
    const int lane = t & 63, w = t >> 6;
    const int grp = w >> 2, wq4 = w & 3, tl = t & 255;
    const int q = lane & 15, g = lane >> 4;
    const int pq = blockIdx.x & 15;
    const int h = (blockIdx.x >> 4) & 15;
    const int b = blockIdx.x >> 8;
    const int qtA = pq, qtB = 31 - pq;
    const int qt1 = grp ? qtB : qtA;
    const unsigned short* qkvu = (const unsigned short*)qkv;
    const size_t rowbase = (size_t)(b * SS) * 3072;
    unsigned short* Kb = K_lds[grp];
    unsigned short* Vb = Vt_lds[grp];
    unsigned short* Pw = &P_lds[w * 1024];
    unsigned short* op = (unsigned short*)o;

    int qgc = qt1 * 64 + wq4 * 16 + q;
    short8 qfc[2];
    #pragma unroll
    for (int kk = 0; kk < 2; ++kk)
        qfc[kk] = *(const short8*)(qkvu + rowbase + (size_t)qgc * 3072 + h * HSZ + kk * 32 + g * 8);

    f32x4 oacc[4] = {};
    float m_run = -1e30f, l_run = 0.f;

    for (int it = 0; it <= pq; ++it) {
        __syncthreads();
        stage_kv(qkvu, rowbase, h, it * 64, tl, Kb, Vb);
        __syncthreads();
        flash_tile(Kb, Vb, Pw, qfc, qgc, it * 64, q, g, m_run, l_run, oacc);
    }

    if (grp == 0) {
        #pragma unroll
        for (int j = 0; j < 4; ++j) {
            float lj = __shfl(l_run, g * 4 + j, 64);
            float inv = 1.f / lj;
            int orow = qtA * 64 + wq4 * 16 + g * 4 + j;
            #pragma unroll
            for (int dn = 0; dn < 4; ++dn)
                op[(size_t)(b * SS + orow) * DD + h * HSZ + dn * 16 + q] = f2bf(oacc[dn][j] * inv);
        }
        qgc = qtB * 64 + wq4 * 16 + q;
        #pragma unroll
        for (int kk = 0; kk < 2; ++kk)
            qfc[kk] = *(const short8*)(qkvu + rowbase + (size_t)qgc * 3072 + h * HSZ + kk * 32 + g * 8);
        m_run = -1e30f; l_run = 0.f;
        #pragma unroll
        for (int dn = 0; dn < 4; ++dn) oacc[dn] = f32x4{0.f, 0.f, 0.f, 0.f};
    }

    for (int it2 = 0; it2 < 16 - pq; ++it2) {
        int tile = grp ? (pq + 1 + it2) : (16 + it2);
        bool active = grp ? (tile <= 15) : true;
        __syncthreads();
        if (active) stage_kv(qkvu, rowbase, h, tile * 64, tl, Kb, Vb);
        __syncthreads();
        if (active) flash_tile(Kb, Vb, Pw, qfc, qgc, tile * 64, q, g, m_run, l_run, oacc);
    }

    __syncthreads();
    float* obuf = (float*)K_lds;
    float* mlbuf = (float*)P_lds;
    if (grp == 0) {
        #pragma unroll
        for (int dn = 0; dn < 4; ++dn)
            #pragma unroll
            for (int j = 0; j < 4; ++j)
                obuf[wq4 * 1024 + lane * 16 + dn * 4 + j] = oacc[dn][j];
        if (g == 0) { mlbuf[wq4 * 32 + q] = m_run; mlbuf[wq4 * 32 + 16 + q] = l_run; }
    }
    __syncthreads();
    if (grp == 1) {
        float mA = mlbuf[wq4 * 32 + q];
        float lA = mlbuf[wq4 * 32 + 16 + q];
        float mM = fmaxf(m_run, mA);
        float sB = __expf(m_run - mM);
        float sA = __expf(mA - mM);
        float lM = l_run * sB + lA * sA;
        #pragma unroll
        for (int j = 0; j < 4; ++j) {
            float sBj = __shfl(sB, g * 4 + j, 64);
            float sAj = __shfl(sA, g * 4 + j, 64);
            float lMj = __shfl(lM, g * 4 + j, 64);
            float inv = 1.f / lMj;
            int orow = qtB * 64 + wq4 * 16 + g * 4 + j;
            #pragma unroll
            for (int dn = 0; dn < 4; ++dn) {
                float oA = obuf[wq4 * 1024 + lane * 16 + dn * 4 + j];
                float vv = (oacc[dn][j] * sBj + oA * sAj) * inv;
                op[(size_t)(b * SS + orow) * DD + h * HSZ + dn * 16 + q] = f2bf(vv);
            }
        }
    }
}

// ---------------- launch ----------------
extern "C" void kernel_launch(void* const* d_in, const int* in_sizes, int n_in,
                              void* d_out, int out_size, void* d_ws, size_t ws_size,
                              hipStream_t stream)
{
    const float* x      = (const float*)d_in[0];
    const float* wq     = (const float*)d_in[1];
    const float* wk     = (const float*)d_in[2];
    const float* wv     = (const float*)d_in[3];
    const float* proj_w = (const float*)d_in[4];
    const float* proj_b = (const float*)d_in[5];
    const float* ff1_w  = (const float*)d_in[6];
    const float* ff1_b  = (const float*)d_in[7];
    const float* ff2_w  = (const float*)d_in[8];
    const float* ff2_b  = (const float*)d_in[9];
    const float* ln1_g  = (const float*)d_in[10];
    const float* ln1_b  = (const float*)d_in[11];
    const float* ln2_g  = (const float*)d_in[12];
    const float* ln2_b  = (const float*)d_in[13];
    float* out = (float*)d_out;

    char* ws = (char*)d_ws;
    const size_t MB = 1ull << 20;
    __hip_bfloat16* h     = (__hip_bfloat16*)(ws);              // 16MB (h / h2)
    __hip_bfloat16* qkv   = (__hip_bfloat16*)(ws + 16 * MB);    // 48MB
    __hip_bfloat16* obuf  = (__hip_bfloat16*)(ws + 64 * MB);    // 16MB
    float*          x1    = (float*)(ws + 80 * MB);             // 32MB
    __hip_bfloat16* wqkvT = (__hip_bfloat16*)(ws + 112 * MB);   // 6MB
    __hip_bfloat16* projT = (__hip_bfloat16*)(ws + 118 * MB);   // 2MB
    __hip_bfloat16* ff1T  = (__hip_bfloat16*)(ws + 120 * MB);   // 8MB
    __hip_bfloat16* ff2T  = (__hip_bfloat16*)(ws + 128 * MB);   // 8MB
    __hip_bfloat16* f1    = (__hip_bfloat16*)(ws + 16 * MB);    // 64MB, aliases qkv+obuf (dead by then)

    const int ROWS = BB * SS;   // 8192

    pack_qkv_kernel<<<(3 * DD * DD) / 256, 256, 0, stream>>>(wq, wk, wv, wqkvT);
    pack_T_kernel<<<(DD * DD) / 256, 256, 0, stream>>>(proj_w, projT, DD, DD);
    pack_T_kernel<<<(DD * DFF) / 256, 256, 0, stream>>>(ff1_w, ff1T, DD, DFF);
    pack_T_kernel<<<(DFF * DD) / 256, 256, 0, stream>>>(ff2_w, ff2T, DFF, DD);

    ln_kernel<<<ROWS, 256, 0, stream>>>(x, ln1_g, ln1_b, h);
    gemm_kernel<256, false, false, false, false><<<(ROWS / 256) * (3 * DD / 256), 512, 0, stream>>>(
        h, wqkvT, nullptr, nullptr, qkv, ROWS, 3 * DD, DD, 3 * DD / 256);
    attn_kernel<<<BB * HH * 16, 512, 0, stream>>>(qkv, obuf);
    gemm_kernel<128, true, false, true, true><<<(ROWS / 256) * (DD / 128), 512, 0, stream>>>(
        obuf, projT, proj_b, x, x1, ROWS, DD, DD, DD / 128);
    ln_kernel<<<ROWS, 256, 0, stream>>>(x1, ln2_g, ln2_b, h);
    gemm_kernel<256, true, true, false, false><<<(ROWS / 256) * (DFF / 256), 512, 0, stream>>>(
        h, ff1T, ff1_b, nullptr, f1, ROWS, DFF, DD, DFF / 256);
    gemm_kernel<128, true, false, true, true><<<(ROWS / 256) * (DD / 128), 512, 0, stream>>>(
        f1, ff2T, ff2_b, x1, out, ROWS, DD, DFF, DD / 128);
}